// Round 1
// baseline (162.296 us; speedup 1.0000x reference)
//
#include <hip/hip_runtime.h>
#include <math.h>

#define B_TOTAL 16384
#define F_TOTAL 256
#define H1 32
#define H2 16
#define FPB 32     // features per block (ngroups = 8)
#define RPB 128    // rows per block (4 waves x 32 rows)
#define NGRP (F_TOTAL / FPB)      // 8
#define NCHUNK (B_TOTAL / RPB)    // 128

typedef _Float16 f16;
typedef __attribute__((ext_vector_type(2))) _Float16 f16x2;
typedef __attribute__((ext_vector_type(8))) _Float16 f16x8;
typedef __attribute__((ext_vector_type(4))) float floatx4;
typedef __attribute__((ext_vector_type(2))) float floatx2;

union F8 { uint4 u; f16x2 h2[4]; f16x8 h8; };

// ---------- pack: W2 -> f16 hi/lo B-frags; W1/b1 -> f16 per-q records;
// b2/W3 -> pre-splatted {b2,b2,w3,w3} float4; b3 -> per-group sequential
// sums (bit-identical to the old in-main loop); zero election counters.
// One block per feature, 64 lanes. ----------
__global__ __launch_bounds__(64) void nam_pack(
    const float* __restrict__ W1, const float* __restrict__ b1,
    const float* __restrict__ W2, const float* __restrict__ b2,
    const float* __restrict__ W3, const float* __restrict__ b3,
    uint4* __restrict__ pkB,      // [F][2][64] uint4: hi frags then lo frags
    uint4* __restrict__ pkW,      // [F][4][2] uint4: {w1 8xf16, b1 8xf16} per q
    float4* __restrict__ pkE,     // [F][16]: {b2,b2,w3,w3} per n
    float* __restrict__ b3g,      // [NGRP] sequential group sums of b3
    int* __restrict__ cnt)        // [NCHUNK] election counters (zeroed here)
{
    const int f = blockIdx.x;
    const int lane = threadIdx.x;
    const int n = lane & 15, q = lane >> 4;

    // B-frag: lane holds B[k=q*8+j][n], hi = f16 RNE, lo = f16(w - hi)
    F8 H, L;
    #pragma unroll
    for (int j = 0; j < 8; ++j) {
        float w = W2[(size_t)f * (H1 * H2) + (q * 8 + j) * H2 + n];
        f16 hi = (f16)w;
        H.h8[j] = hi;
        L.h8[j] = (f16)(w - (float)hi);
    }
    pkB[(size_t)f * 128 + lane] = H.u;
    pkB[(size_t)f * 128 + 64 + lane] = L.u;

    if (n == 0) {   // one lane per q builds the w1/b1 record
        F8 A, Bb;
        #pragma unroll
        for (int j = 0; j < 8; ++j) {
            A.h8[j]  = (f16)W1[(size_t)f * H1 + q * 8 + j];
            Bb.h8[j] = (f16)b1[(size_t)f * H1 + q * 8 + j];
        }
        pkW[((size_t)f * 4 + q) * 2]     = A.u;
        pkW[((size_t)f * 4 + q) * 2 + 1] = Bb.u;
    }
    if (q == 0) {   // one lane per n builds pre-splatted {b2,b2,w3,w3}
        float bb = b2[(size_t)f * H2 + n];
        float ww = W3[(size_t)f * H2 + n];
        float4 e; e.x = bb; e.y = bb; e.z = ww; e.w = ww;
        pkE[(size_t)f * 16 + n] = e;
    }
    // sequential b3 group sum — same order as the old per-thread loop
    if (lane == 0 && (f & (FPB - 1)) == 0) {
        float s = 0.f;
        #pragma unroll
        for (int i = 0; i < FPB; ++i) s += b3[f + i];
        b3g[f / FPB] = s;
    }
    // zero the last-block election counters (runs after the ws poison,
    // before nam_main, stream-ordered)
    if (lane == 0 && f < NCHUNK) cnt[f] = 0;
}

// ---------- main: block = 128 rows x 32 features; wave = 32 rows (2 M16
// tiles sharing B/w1/b1/b2w3). Operands staged to LDS once -> zero
// barriers in the K-loop. B-frags stream from global, depth-2 prefetch.
// x staged PRE-SPLATTED f16x2 (cvt hoisted out of the loop); epilogue on
// float2 vectors (v_pk_add_f32 / v_pk_fma_f32); MFMA seeded from a
// loop-invariant zero4 (no per-iter acc re-zeroing). Math path is
// bit-identical per element to the 91.8us passing kernel.
// Finish is FUSED: last block per row-chunk (atomic election) sums the 8
// partials in the same g=0..7 order and writes sigmoid. ----------
__global__ __launch_bounds__(256, 4) void nam_main(
    const float* __restrict__ x,   // [B, F]
    const uint4* __restrict__ pkB,
    const uint4* __restrict__ pkW,
    const float4* __restrict__ pkE,
    const float* __restrict__ b3g,
    float* __restrict__ part,      // [8][B], fully overwritten
    int* __restrict__ cnt,         // [NCHUNK], zeroed by nam_pack
    float* __restrict__ out)       // [B]
{
    __shared__ f16x2  xs[FPB][RPB];        // 16 KB, pre-splatted {h,h}
    __shared__ uint4  w1b1s[FPB * 4 * 2];  // 4 KB
    __shared__ float4 b2w3s[FPB * 16];     // 8 KB, {b2,b2,w3,w3}
    __shared__ int    elect;

    const int t = threadIdx.x;
    const int lane = t & 63;
    const int wave = t >> 6;
    const int n = lane & 15, q = lane >> 4;
    const int b0 = blockIdx.x * RPB;
    const int f0 = blockIdx.y * FPB;

    // ---- one-time staging ----
    {
        int r = t >> 1, c0 = (t & 1) * 16;          // 16 feats per half-row
        const float4* xrow = (const float4*)(x + (size_t)(b0 + r) * F_TOTAL + f0 + c0);
        #pragma unroll
        for (int i = 0; i < 4; ++i) {
            float4 v = xrow[i];
            f16 h0 = (f16)v.x, h1 = (f16)v.y, h2 = (f16)v.z, h3 = (f16)v.w;
            xs[c0 + i * 4 + 0][r] = (f16x2){h0, h0};
            xs[c0 + i * 4 + 1][r] = (f16x2){h1, h1};
            xs[c0 + i * 4 + 2][r] = (f16x2){h2, h2};
            xs[c0 + i * 4 + 3][r] = (f16x2){h3, h3};
        }
    }
    w1b1s[t] = pkW[(size_t)f0 * 8 + t];                            // 4 KB
    ((uint4*)b2w3s)[t]       = ((const uint4*)pkE)[(size_t)f0 * 16 + t];        // 8 KB
    ((uint4*)b2w3s)[t + 256] = ((const uint4*)pkE)[(size_t)f0 * 16 + t + 256];
    __syncthreads();

    const uint4* pB = pkB + (size_t)f0 * 128 + lane;
    uint4 bh[2], bl[2];
    bh[0] = pB[0];   bl[0] = pB[64];
    bh[1] = pB[128]; bl[1] = pB[192];

    floatx2 acc1a = {0.f, 0.f}, acc1b = {0.f, 0.f};
    floatx2 acc2a = {0.f, 0.f}, acc2b = {0.f, 0.f};
    const floatx4 zero4 = {0.f, 0.f, 0.f, 0.f};
    const floatx2 zero2 = {0.f, 0.f};
    const int rb = wave * 32;
    const f16x2 z2 = {(f16)0, (f16)0};

    #pragma unroll 2
    for (int fi = 0; fi < FPB; ++fi) {
        F8 Bh, Bl;
        Bh.u = bh[fi & 1];
        Bl.u = bl[fi & 1];
        int nf = (fi + 2 < FPB) ? fi + 2 : fi;   // clamped prefetch
        bh[fi & 1] = pB[(size_t)nf * 128];
        bl[fi & 1] = pB[(size_t)nf * 128 + 64];

        const f16x2 x1 = xs[fi][rb + n];         // pre-splatted
        const f16x2 x2 = xs[fi][rb + 16 + n];
        F8 W, Bi;
        W.u  = w1b1s[(fi * 4 + q) * 2];
        Bi.u = w1b1s[(fi * 4 + q) * 2 + 1];

        F8 A1, A2;
        #pragma unroll
        for (int tt = 0; tt < 4; ++tt) {
            f16x2 h1 = x1 * W.h2[tt] + Bi.h2[tt];   // v_pk_fma_f16
            f16x2 h2 = x2 * W.h2[tt] + Bi.h2[tt];
            A1.h2[tt] = __builtin_elementwise_max(h1, z2);  // v_pk_max_f16
            A2.h2[tt] = __builtin_elementwise_max(h2, z2);
        }

        floatx4 c1 = __builtin_amdgcn_mfma_f32_16x16x32_f16(A1.h8, Bh.h8, zero4, 0, 0, 0);
        c1 = __builtin_amdgcn_mfma_f32_16x16x32_f16(A1.h8, Bl.h8, c1, 0, 0, 0);
        floatx4 c2 = __builtin_amdgcn_mfma_f32_16x16x32_f16(A2.h8, Bh.h8, zero4, 0, 0, 0);
        c2 = __builtin_amdgcn_mfma_f32_16x16x32_f16(A2.h8, Bl.h8, c2, 0, 0, 0);

        const float4 bw = b2w3s[fi * 16 + n];    // one ds_read_b128
        const floatx2 bx = {bw.x, bw.y};         // {b2, b2}
        const floatx2 by = {bw.z, bw.w};         // {w3, w3}
        floatx2 u;
        u = (floatx2){c1[0], c1[1]} + bx;        // v_pk_add_f32
        u = __builtin_elementwise_max(u, zero2);
        acc1a = __builtin_elementwise_fma(u, by, acc1a);   // v_pk_fma_f32
        u = (floatx2){c1[2], c1[3]} + bx;
        u = __builtin_elementwise_max(u, zero2);
        acc1b = __builtin_elementwise_fma(u, by, acc1b);
        u = (floatx2){c2[0], c2[1]} + bx;
        u = __builtin_elementwise_max(u, zero2);
        acc2a = __builtin_elementwise_fma(u, by, acc2a);
        u = (floatx2){c2[2], c2[3]} + bx;
        u = __builtin_elementwise_max(u, zero2);
        acc2b = __builtin_elementwise_fma(u, by, acc2b);
    }

    const float accb3 = b3g[blockIdx.y];   // uniform, precomputed in pack

    floatx4 acc1 = {acc1a.x, acc1a.y, acc1b.x, acc1b.y};
    floatx4 acc2 = {acc2a.x, acc2a.y, acc2b.x, acc2b.y};
    #pragma unroll
    for (int r = 0; r < 4; ++r) {
        float v1 = acc1[r], v2 = acc2[r];
        v1 += __shfl_xor(v1, 1); v2 += __shfl_xor(v2, 1);
        v1 += __shfl_xor(v1, 2); v2 += __shfl_xor(v2, 2);
        v1 += __shfl_xor(v1, 4); v2 += __shfl_xor(v2, 4);
        v1 += __shfl_xor(v1, 8); v2 += __shfl_xor(v2, 8);
        acc1[r] = v1; acc2[r] = v2;
    }
    if (n == 0) {
        // wave covers rows b0+rb .. b0+rb+31; lane (q, n=0) writes rows q*4..q*4+3
        float* dst = part + (size_t)blockIdx.y * B_TOTAL + b0 + rb;
        float4 o1, o2;
        o1.x = acc1[0] + accb3; o1.y = acc1[1] + accb3;
        o1.z = acc1[2] + accb3; o1.w = acc1[3] + accb3;
        o2.x = acc2[0] + accb3; o2.y = acc2[1] + accb3;
        o2.z = acc2[2] + accb3; o2.w = acc2[3] + accb3;
        *(float4*)(dst + q * 4)      = o1;
        *(float4*)(dst + 16 + q * 4) = o2;
    }

    // ---- fused finish: last block per row-chunk sums the 8 partials ----
    __threadfence();                         // release our partial stores (device scope)
    __syncthreads();
    if (t == 0) elect = atomicAdd(&cnt[blockIdx.x], 1);
    __syncthreads();
    if (elect == NGRP - 1) {
        __threadfence();                     // acquire the other 7 groups' stores
        if (t < RPB) {
            const int row = b0 + t;
            float s = 0.f;
            #pragma unroll
            for (int g = 0; g < NGRP; ++g) s += part[(size_t)g * B_TOTAL + row];
            out[row] = 1.0f / (1.0f + expf(-s));
        }
    }
}

extern "C" void kernel_launch(void* const* d_in, const int* in_sizes, int n_in,
                              void* d_out, int out_size, void* d_ws, size_t ws_size,
                              hipStream_t stream) {
    const float* x  = (const float*)d_in[0];
    const float* W1 = (const float*)d_in[1];
    const float* b1 = (const float*)d_in[2];
    const float* W2 = (const float*)d_in[3];
    const float* b2 = (const float*)d_in[4];
    const float* W3 = (const float*)d_in[5];
    const float* b3 = (const float*)d_in[6];
    float* out = (float*)d_out;

    // ws layout (~1.15 MB used; ws is ~268 MB, harness poison-fills it — that
    // poison is the ~86us floor in dur_us, outside kernel control):
    //   [0, 512K)      pkB   f16 hi/lo B-frags
    //   [512K, 544K)   pkW   f16 w1/b1 records
    //   [544K, 608K)   pkE   {b2,b2,w3,w3} float4
    //   [608K, 609K)   b3g   per-group b3 sums (32 B)
    //   [609K, 640K)   cnt   election counters (512 B, zeroed by nam_pack)
    //   [640K, 1152K)  part  [8][B] fp32 partials (every slot stored each launch)
    char* ws = (char*)d_ws;
    uint4*  pkB   = (uint4*)ws;
    uint4*  pkW   = (uint4*)(ws + (512 << 10));
    float4* pkE   = (float4*)(ws + (544 << 10));
    float*  b3g   = (float*)(ws + (608 << 10));
    int*    cnt   = (int*)(ws + (609 << 10));
    float*  partp = (float*)(ws + (640 << 10));

    nam_pack<<<F_TOTAL, 64, 0, stream>>>(W1, b1, W2, b2, W3, b3, pkB, pkW, pkE, b3g, cnt);

    dim3 grid(NCHUNK, NGRP);   // (128, 8)
    nam_main<<<grid, 256, 0, stream>>>(x, pkB, pkW, pkE, b3g, partp, cnt, out);
}

// Round 2
// 90.450 us; speedup vs baseline: 1.7943x; 1.7943x over previous
//
#include <hip/hip_runtime.h>
#include <math.h>

#define B_TOTAL 16384
#define F_TOTAL 256
#define H1 32
#define H2 16
#define FPB 32     // features per block (ngroups = 8)
#define RPB 128    // rows per block (4 waves x 32 rows)
#define NGRP (F_TOTAL / FPB)      // 8

typedef _Float16 f16;
typedef __attribute__((ext_vector_type(2))) _Float16 f16x2;
typedef __attribute__((ext_vector_type(8))) _Float16 f16x8;
typedef __attribute__((ext_vector_type(4))) float floatx4;
typedef __attribute__((ext_vector_type(2))) float floatx2;

union F8 { uint4 u; f16x2 h2[4]; f16x8 h8; };

// ---------- pack: W2 -> f16 hi/lo B-frags; W1/b1 -> f16 per-q records;
// b2/W3 -> pre-splatted {b2,b2,w3,w3} float4; b3 -> per-group sequential
// sums (bit-identical to summing b3s[0..31] in-main). One block per
// feature, 64 lanes. ----------
__global__ __launch_bounds__(64) void nam_pack(
    const float* __restrict__ W1, const float* __restrict__ b1,
    const float* __restrict__ W2, const float* __restrict__ b2,
    const float* __restrict__ W3, const float* __restrict__ b3,
    uint4* __restrict__ pkB,      // [F][2][64] uint4: hi frags then lo frags
    uint4* __restrict__ pkW,      // [F][4][2] uint4: {w1 8xf16, b1 8xf16} per q
    float4* __restrict__ pkE,     // [F][16]: {b2,b2,w3,w3} per n
    float* __restrict__ b3g)      // [NGRP] sequential group sums of b3
{
    const int f = blockIdx.x;
    const int lane = threadIdx.x;
    const int n = lane & 15, q = lane >> 4;

    // B-frag: lane holds B[k=q*8+j][n], hi = f16 RNE, lo = f16(w - hi)
    F8 H, L;
    #pragma unroll
    for (int j = 0; j < 8; ++j) {
        float w = W2[(size_t)f * (H1 * H2) + (q * 8 + j) * H2 + n];
        f16 hi = (f16)w;
        H.h8[j] = hi;
        L.h8[j] = (f16)(w - (float)hi);
    }
    pkB[(size_t)f * 128 + lane] = H.u;
    pkB[(size_t)f * 128 + 64 + lane] = L.u;

    if (n == 0) {   // one lane per q builds the w1/b1 record
        F8 A, Bb;
        #pragma unroll
        for (int j = 0; j < 8; ++j) {
            A.h8[j]  = (f16)W1[(size_t)f * H1 + q * 8 + j];
            Bb.h8[j] = (f16)b1[(size_t)f * H1 + q * 8 + j];
        }
        pkW[((size_t)f * 4 + q) * 2]     = A.u;
        pkW[((size_t)f * 4 + q) * 2 + 1] = Bb.u;
    }
    if (q == 0) {   // one lane per n builds pre-splatted {b2,b2,w3,w3}
        float bb = b2[(size_t)f * H2 + n];
        float ww = W3[(size_t)f * H2 + n];
        float4 e; e.x = bb; e.y = bb; e.z = ww; e.w = ww;
        pkE[(size_t)f * 16 + n] = e;
    }
    // sequential b3 group sum — same order as the old per-thread loop
    if (lane == 0 && (f & (FPB - 1)) == 0) {
        float s = 0.f;
        #pragma unroll
        for (int i = 0; i < FPB; ++i) s += b3[f + i];
        b3g[f / FPB] = s;
    }
}

// ---------- main: block = 128 rows x 32 features; wave = 32 rows (2 M16
// tiles sharing B/w1/b1/b2w3). Operands staged to LDS once -> zero
// barriers in the K-loop. B-frags stream from global, depth-2 prefetch.
// x staged PRE-SPLATTED f16x2 (cvt hoisted out of the loop); epilogue on
// float2 vectors (v_pk_add_f32 / v_pk_fma_f32); MFMA seeded from a
// loop-invariant zero4. Math path bit-identical per element to the
// 91.8us passing kernel. NO fences / NO election — the device-scope
// __threadfence() experiment (round 1) cost ~90us in L2 wb/inv traffic
// across 1024 blocks; a separate finish kernel is far cheaper. ----------
__global__ __launch_bounds__(256, 4) void nam_main(
    const float* __restrict__ x,   // [B, F]
    const uint4* __restrict__ pkB,
    const uint4* __restrict__ pkW,
    const float4* __restrict__ pkE,
    const float* __restrict__ b3g,
    float* __restrict__ part)      // [8][B], fully overwritten
{
    __shared__ f16x2  xs[FPB][RPB];        // 16 KB, pre-splatted {h,h}
    __shared__ uint4  w1b1s[FPB * 4 * 2];  // 4 KB
    __shared__ float4 b2w3s[FPB * 16];     // 8 KB, {b2,b2,w3,w3}

    const int t = threadIdx.x;
    const int lane = t & 63;
    const int wave = t >> 6;
    const int n = lane & 15, q = lane >> 4;
    const int b0 = blockIdx.x * RPB;
    const int f0 = blockIdx.y * FPB;

    // ---- one-time staging ----
    {
        int r = t >> 1, c0 = (t & 1) * 16;          // 16 feats per half-row
        const float4* xrow = (const float4*)(x + (size_t)(b0 + r) * F_TOTAL + f0 + c0);
        #pragma unroll
        for (int i = 0; i < 4; ++i) {
            float4 v = xrow[i];
            f16 h0 = (f16)v.x, h1 = (f16)v.y, h2 = (f16)v.z, h3 = (f16)v.w;
            xs[c0 + i * 4 + 0][r] = (f16x2){h0, h0};
            xs[c0 + i * 4 + 1][r] = (f16x2){h1, h1};
            xs[c0 + i * 4 + 2][r] = (f16x2){h2, h2};
            xs[c0 + i * 4 + 3][r] = (f16x2){h3, h3};
        }
    }
    w1b1s[t] = pkW[(size_t)f0 * 8 + t];                            // 4 KB
    ((uint4*)b2w3s)[t]       = ((const uint4*)pkE)[(size_t)f0 * 16 + t];        // 8 KB
    ((uint4*)b2w3s)[t + 256] = ((const uint4*)pkE)[(size_t)f0 * 16 + t + 256];
    __syncthreads();

    const uint4* pB = pkB + (size_t)f0 * 128 + lane;
    uint4 bh[2], bl[2];
    bh[0] = pB[0];   bl[0] = pB[64];
    bh[1] = pB[128]; bl[1] = pB[192];

    floatx2 acc1a = {0.f, 0.f}, acc1b = {0.f, 0.f};
    floatx2 acc2a = {0.f, 0.f}, acc2b = {0.f, 0.f};
    const floatx4 zero4 = {0.f, 0.f, 0.f, 0.f};
    const floatx2 zero2 = {0.f, 0.f};
    const int rb = wave * 32;
    const f16x2 z2 = {(f16)0, (f16)0};

    #pragma unroll 2
    for (int fi = 0; fi < FPB; ++fi) {
        F8 Bh, Bl;
        Bh.u = bh[fi & 1];
        Bl.u = bl[fi & 1];
        int nf = (fi + 2 < FPB) ? fi + 2 : fi;   // clamped prefetch
        bh[fi & 1] = pB[(size_t)nf * 128];
        bl[fi & 1] = pB[(size_t)nf * 128 + 64];

        const f16x2 x1 = xs[fi][rb + n];         // pre-splatted
        const f16x2 x2 = xs[fi][rb + 16 + n];
        F8 W, Bi;
        W.u  = w1b1s[(fi * 4 + q) * 2];
        Bi.u = w1b1s[(fi * 4 + q) * 2 + 1];

        F8 A1, A2;
        #pragma unroll
        for (int tt = 0; tt < 4; ++tt) {
            f16x2 h1 = x1 * W.h2[tt] + Bi.h2[tt];   // v_pk_fma_f16
            f16x2 h2 = x2 * W.h2[tt] + Bi.h2[tt];
            A1.h2[tt] = __builtin_elementwise_max(h1, z2);  // v_pk_max_f16
            A2.h2[tt] = __builtin_elementwise_max(h2, z2);
        }

        floatx4 c1 = __builtin_amdgcn_mfma_f32_16x16x32_f16(A1.h8, Bh.h8, zero4, 0, 0, 0);
        c1 = __builtin_amdgcn_mfma_f32_16x16x32_f16(A1.h8, Bl.h8, c1, 0, 0, 0);
        floatx4 c2 = __builtin_amdgcn_mfma_f32_16x16x32_f16(A2.h8, Bh.h8, zero4, 0, 0, 0);
        c2 = __builtin_amdgcn_mfma_f32_16x16x32_f16(A2.h8, Bl.h8, c2, 0, 0, 0);

        const float4 bw = b2w3s[fi * 16 + n];    // one ds_read_b128
        const floatx2 bx = {bw.x, bw.y};         // {b2, b2}
        const floatx2 by = {bw.z, bw.w};         // {w3, w3}
        floatx2 u;
        u = (floatx2){c1[0], c1[1]} + bx;        // v_pk_add_f32
        u = __builtin_elementwise_max(u, zero2);
        acc1a = __builtin_elementwise_fma(u, by, acc1a);   // v_pk_fma_f32
        u = (floatx2){c1[2], c1[3]} + bx;
        u = __builtin_elementwise_max(u, zero2);
        acc1b = __builtin_elementwise_fma(u, by, acc1b);
        u = (floatx2){c2[0], c2[1]} + bx;
        u = __builtin_elementwise_max(u, zero2);
        acc2a = __builtin_elementwise_fma(u, by, acc2a);
        u = (floatx2){c2[2], c2[3]} + bx;
        u = __builtin_elementwise_max(u, zero2);
        acc2b = __builtin_elementwise_fma(u, by, acc2b);
    }

    const float accb3 = b3g[blockIdx.y];   // uniform, precomputed in pack

    floatx4 acc1 = {acc1a.x, acc1a.y, acc1b.x, acc1b.y};
    floatx4 acc2 = {acc2a.x, acc2a.y, acc2b.x, acc2b.y};
    #pragma unroll
    for (int r = 0; r < 4; ++r) {
        float v1 = acc1[r], v2 = acc2[r];
        v1 += __shfl_xor(v1, 1); v2 += __shfl_xor(v2, 1);
        v1 += __shfl_xor(v1, 2); v2 += __shfl_xor(v2, 2);
        v1 += __shfl_xor(v1, 4); v2 += __shfl_xor(v2, 4);
        v1 += __shfl_xor(v1, 8); v2 += __shfl_xor(v2, 8);
        acc1[r] = v1; acc2[r] = v2;
    }
    if (n == 0) {
        // wave covers rows b0+rb .. b0+rb+31; lane (q, n=0) writes rows q*4..q*4+3
        float* dst = part + (size_t)blockIdx.y * B_TOTAL + b0 + rb;
        float4 o1, o2;
        o1.x = acc1[0] + accb3; o1.y = acc1[1] + accb3;
        o1.z = acc1[2] + accb3; o1.w = acc1[3] + accb3;
        o2.x = acc2[0] + accb3; o2.y = acc2[1] + accb3;
        o2.z = acc2[2] + accb3; o2.w = acc2[3] + accb3;
        *(float4*)(dst + q * 4)      = o1;
        *(float4*)(dst + 16 + q * 4) = o2;
    }
}

__global__ __launch_bounds__(256) void nam_finish(
    const float* __restrict__ part, float* __restrict__ out)
{
    const int b = blockIdx.x * 256 + threadIdx.x;
    float s = 0.f;
    #pragma unroll
    for (int g = 0; g < NGRP; ++g) s += part[(size_t)g * B_TOTAL + b];
    out[b] = 1.0f / (1.0f + expf(-s));
}

extern "C" void kernel_launch(void* const* d_in, const int* in_sizes, int n_in,
                              void* d_out, int out_size, void* d_ws, size_t ws_size,
                              hipStream_t stream) {
    const float* x  = (const float*)d_in[0];
    const float* W1 = (const float*)d_in[1];
    const float* b1 = (const float*)d_in[2];
    const float* W2 = (const float*)d_in[3];
    const float* b2 = (const float*)d_in[4];
    const float* W3 = (const float*)d_in[5];
    const float* b3 = (const float*)d_in[6];
    float* out = (float*)d_out;

    // ws layout (~1.2 MB used; harness poison-fills the full ws — that
    // poison (~86us of fillBuffer @6.3TB/s) is the dur_us floor, outside
    // kernel control):
    //   [0, 512K)      pkB   f16 hi/lo B-frags
    //   [512K, 544K)   pkW   f16 w1/b1 records
    //   [544K, 608K)   pkE   {b2,b2,w3,w3} float4
    //   [608K, 612K)   b3g   per-group b3 sums
    //   [640K, 1152K)  part  [8][B] fp32 partials (every slot stored each launch)
    char* ws = (char*)d_ws;
    uint4*  pkB   = (uint4*)ws;
    uint4*  pkW   = (uint4*)(ws + (512 << 10));
    float4* pkE   = (float4*)(ws + (544 << 10));
    float*  b3g   = (float*)(ws + (608 << 10));
    float*  partp = (float*)(ws + (640 << 10));

    nam_pack<<<F_TOTAL, 64, 0, stream>>>(W1, b1, W2, b2, W3, b3, pkB, pkW, pkE, b3g);

    dim3 grid(B_TOTAL / RPB, NGRP);   // (128, 8)
    nam_main<<<grid, 256, 0, stream>>>(x, pkB, pkW, pkE, b3g, partp);

    nam_finish<<<B_TOTAL / 256, 256, 0, stream>>>(partp, out);
}